// Round 13
// baseline (465.582 us; speedup 1.0000x reference)
//
#include <hip/hip_runtime.h>
#include <hip/hip_bf16.h>

typedef __bf16 bf16;
typedef __attribute__((ext_vector_type(8))) __bf16 bf16x8;
typedef __attribute__((ext_vector_type(4))) float f32x4;

#define GLOAD_LDS16(g, l)                                                        \
    __builtin_amdgcn_global_load_lds(                                            \
        (const __attribute__((address_space(1))) void*)(g),                      \
        (__attribute__((address_space(3))) void*)(l), 16, 0, 0)

#define WAITV(n) asm volatile("s_waitcnt vmcnt(" #n ")" ::: "memory")
#define LGKM0()  asm volatile("s_waitcnt lgkmcnt(0)" ::: "memory")
#define BAR()    __builtin_amdgcn_s_barrier()
#define SCHEDB() __builtin_amdgcn_sched_barrier(0)

// ---------------- fp32 -> bf16 conversion (vectorized, grid-stride) ----------------
__global__ __launch_bounds__(256) void cvt_f32_bf16(
    const float* __restrict__ src, bf16* __restrict__ dst, int n16)
{
    int idx = blockIdx.x * 256 + threadIdx.x;
    const int stride = gridDim.x * 256;
    for (int i = idx; i < n16; i += stride) {
        const float* p = src + (size_t)i * 16;
        f32x4 a = *(const f32x4*)p;
        f32x4 b = *(const f32x4*)(p + 4);
        f32x4 c = *(const f32x4*)(p + 8);
        f32x4 d = *(const f32x4*)(p + 12);
        bf16x8 h0, h1;
#pragma unroll
        for (int j = 0; j < 4; ++j) {
            h0[j] = (bf16)a[j]; h0[4 + j] = (bf16)b[j];
            h1[j] = (bf16)c[j]; h1[4 + j] = (bf16)d[j];
        }
        bf16* q = dst + (size_t)i * 16;
        *(bf16x8*)q = h0;
        *(bf16x8*)(q + 8) = h1;
    }
}

// ---- 8-phase GEMM, corrected schedule: C[M][N] = A[M][K]*B[N][K]^T + bias ----
// BM=BN=256, BK=64, 8 waves 2Mx4N -> per-wave 128x64 (acc 128 VGPR, reuse 42.7).
// LDS 128KB: buf b (= tile parity) x {A0,A1,B0,B1} slots of 128x64.
// Slot lifetimes per iter (buf0=tile t0 even, buf1=t0+1): buf0.B dies after P2-bar,
// buf0.A after P3-bar, buf1.B after P6-bar, buf1.A after P7-bar. Stages strictly after
// death: P3:B[t+2], P4:A[t+2], P7:B[t+3], P8:A[t+3] (4 gloads/wave each).
// vmcnt: WAITV(8)@P4 retires tile t+1 (16 in flight) before P5 reads buf1;
// WAITV(8)@P8 retires tile t+2 before next P1 reads buf0. Last iter: WAITV(0)@P4.
// Swizzle (r6 HW-verified 0-conflict): phys 16B-slot s of row r holds chunk s^(r&7).
template <int OUT_BF16>
__global__ __launch_bounds__(512, 2) void gemm_8p(
    const bf16* __restrict__ A, const bf16* __restrict__ B,
    const float* __restrict__ bias, void* __restrict__ Cout,
    int K, int ldc, int nbx)
{
    __shared__ bf16 lds[2 * 4 * 8192];   // buf*32768 + slot*8192; slots: A0,A1,B0,B1

    const int cpx = gridDim.x >> 3;      // bijective XCD swizzle (grid % 8 == 0)
    const int swz = ((int)blockIdx.x & 7) * cpx + ((int)blockIdx.x >> 3);
    const int bx = swz % nbx, by = swz / nbx;
    const int brow = by * 256, bcol = bx * 256;

    const int tid  = threadIdx.x;
    const int wv   = tid >> 6, lane = tid & 63;
    const int lo   = lane & 15, hi = lane >> 4;
    const int wrp  = wv >> 2, wcp = wv & 3;   // wave owns rows wrp*128+[0,128), cols wcp*64+[0,64)

    const int srow = lane >> 3;                       // row-in-chunk 0..7
    const int scol = ((lane & 7) ^ (lane >> 3)) * 8;  // pre-swizzled global col (elems)

    f32x4 acc[8][4];
#pragma unroll
    for (int m = 0; m < 8; ++m)
#pragma unroll
        for (int n = 0; n < 4; ++n)
            acc[m][n] = (f32x4){0.f, 0.f, 0.f, 0.f};

    auto STAGEA = [&](int t, int half) {   // A rows half*128..+127 -> buf(t&1) slot half
        bf16* lb = &lds[(t & 1) * 32768 + half * 8192];
        const bf16* gb = A + (size_t)(brow + half * 128) * K + t * 64;
#pragma unroll
        for (int j = 0; j < 2; ++j) {
            const int c = wv * 2 + j;
            GLOAD_LDS16(gb + (size_t)(c * 8 + srow) * K + scol, lb + c * 512);
        }
    };
    auto STAGEB = [&](int t, int half) {   // B rows (=out cols) half*128..+127 -> slot 2+half
        bf16* lb = &lds[(t & 1) * 32768 + (2 + half) * 8192];
        const bf16* gb = B + (size_t)(bcol + half * 128) * K + t * 64;
#pragma unroll
        for (int j = 0; j < 2; ++j) {
            const int c = wv * 2 + j;
            GLOAD_LDS16(gb + (size_t)(c * 8 + srow) * K + scol, lb + c * 512);
        }
    };

    bf16x8 af[4][2], bf0[2][2], bf1[2][2];
    auto LDA = [&](int b, int mh) {        // 8 ds_read_b128: wave's A slot, row-half mh
        const bf16* base = &lds[b * 32768 + wrp * 8192];
#pragma unroll
        for (int m = 0; m < 4; ++m)
#pragma unroll
            for (int kk = 0; kk < 2; ++kk)
                af[m][kk] = *(const bf16x8*)&base[(mh * 64 + m * 16 + lo) * 64 + (((kk * 4 + hi) ^ (lo & 7)) * 8)];
    };
    auto LDB = [&](int b, int nh, bf16x8 (&bfr)[2][2]) {   // 4 ds_read_b128
        const bf16* base = &lds[b * 32768 + (2 + (wcp >> 1)) * 8192];
#pragma unroll
        for (int n = 0; n < 2; ++n)
#pragma unroll
            for (int kk = 0; kk < 2; ++kk)
                bfr[n][kk] = *(const bf16x8*)&base[((wcp & 1) * 64 + nh * 32 + n * 16 + lo) * 64 + (((kk * 4 + hi) ^ (lo & 7)) * 8)];
    };

#define MM(mh, nh, BF)                                                                     \
    do {                                                                                   \
        __builtin_amdgcn_s_setprio(1);                                                     \
        _Pragma("unroll")                                                                  \
        for (int m = 0; m < 4; ++m)                                                        \
            _Pragma("unroll")                                                              \
            for (int n = 0; n < 2; ++n)                                                    \
                _Pragma("unroll")                                                          \
                for (int kk = 0; kk < 2; ++kk)                                             \
                    acc[(mh) * 4 + m][(nh) * 2 + n] = __builtin_amdgcn_mfma_f32_16x16x32_bf16( \
                        af[m][kk], BF[n][kk], acc[(mh) * 4 + m][(nh) * 2 + n], 0, 0, 0);   \
        __builtin_amdgcn_s_setprio(0);                                                     \
    } while (0)

    const int nt = K / 64, niter = nt / 2;   // K=4096: nt=64, niter=32

    // prologue: tile0 (8 loads, oldest) then tile1 (8); WAITV(8) retires tile0
    STAGEA(0, 0); STAGEA(0, 1); STAGEB(0, 0); STAGEB(0, 1);
    STAGEA(1, 0); STAGEA(1, 1); STAGEB(1, 0); STAGEB(1, 1);
    WAITV(8); BAR(); SCHEDB();

    for (int it = 0; it < niter; ++it) {
        const int t0 = 2 * it;
        const bool nl = (it + 1 < niter);

        // P1: tile t0 (buf0) quadrant (0,0)
        LDA(0, 0); LDB(0, 0, bf0);
        BAR(); LGKM0(); SCHEDB();
        MM(0, 0, bf0);
        BAR();
        // P2: quadrant (0,1)   [buf0.B last read here]
        LDB(0, 1, bf1);
        BAR(); LGKM0(); SCHEDB();
        MM(0, 1, bf1);
        BAR();
        // P3: quadrant (1,1)   [buf0.A last read here; buf0.B slots dead -> stage B[t+2]]
        LDA(0, 1);
        if (nl) { STAGEB(t0 + 2, 0); STAGEB(t0 + 2, 1); }
        BAR(); LGKM0(); SCHEDB();
        MM(1, 1, bf1);
        BAR();
        // P4: quadrant (1,0)   [regs only; buf0.A dead -> stage A[t+2]]
        if (nl) { STAGEA(t0 + 2, 0); STAGEA(t0 + 2, 1); }
        BAR(); SCHEDB();
        MM(1, 0, bf0);
        if (nl) WAITV(8); else WAITV(0);   // retire tile t0+1 before P5 reads buf1
        BAR(); SCHEDB();

        // P5: tile t0+1 (buf1) quadrant (0,0)
        LDA(1, 0); LDB(1, 0, bf0);
        BAR(); LGKM0(); SCHEDB();
        MM(0, 0, bf0);
        BAR();
        // P6: quadrant (0,1)   [buf1.B last read]
        LDB(1, 1, bf1);
        BAR(); LGKM0(); SCHEDB();
        MM(0, 1, bf1);
        BAR();
        // P7: quadrant (1,1)   [buf1.A last read; buf1.B dead -> stage B[t+3]]
        LDA(1, 1);
        if (nl) { STAGEB(t0 + 3, 0); STAGEB(t0 + 3, 1); }
        BAR(); LGKM0(); SCHEDB();
        MM(1, 1, bf1);
        BAR();
        // P8: quadrant (1,0)   [buf1.A dead -> stage A[t+3]]
        if (nl) { STAGEA(t0 + 3, 0); STAGEA(t0 + 3, 1); }
        BAR(); SCHEDB();
        MM(1, 0, bf0);
        if (nl) { WAITV(8); BAR(); SCHEDB(); }   // retire tile t0+2 before next P1
    }
#undef MM

    // epilogue: C/D layout row=(lane>>4)*4+r, col=lane&15
#pragma unroll
    for (int mi = 0; mi < 8; ++mi) {
        const int row = brow + wrp * 128 + mi * 16 + hi * 4;
#pragma unroll
        for (int ni = 0; ni < 4; ++ni) {
            const int col = bcol + wcp * 64 + ni * 16 + lo;
            const float bv = bias[col];
#pragma unroll
            for (int r = 0; r < 4; ++r) {
                const float v = acc[mi][ni][r] + bv;
                if (OUT_BF16)
                    ((bf16*)Cout)[(size_t)(row + r) * ldc + col] = (bf16)v;
                else
                    ((float*)Cout)[(size_t)(row + r) * ldc + col] = v;
            }
        }
    }
}

// ---- r11-verified single-phase 3-deep GEMM (out-proj: exact 256-block round) ----
template <int OUT_BF16>
__global__ __launch_bounds__(512, 2) void gemm_sp(
    const bf16* __restrict__ A, const bf16* __restrict__ B,
    const float* __restrict__ bias, void* __restrict__ Cout,
    int K, int ldc, int nbx)
{
    constexpr int ASZ = 128 * 64;
    constexpr int BUF = ASZ + 256 * 64;
    __shared__ bf16 lds[3 * BUF];

    int bx, by;
    if ((nbx & 15) == 0) {
        const int r = (int)blockIdx.x & 255;
        const int slot = r >> 3;
        bx = ((int)blockIdx.x >> 8) * 16 + (r & 7) * 2 + (slot >> 4);
        by = slot & 15;
    } else {
        const int cpx = gridDim.x >> 3;
        const int swz = ((int)blockIdx.x & 7) * cpx + ((int)blockIdx.x >> 3);
        bx = swz % nbx; by = swz / nbx;
    }
    const int brow = by * 128, bcol = bx * 256;

    const int tid  = threadIdx.x;
    const int wv   = tid >> 6, lane = tid & 63;
    const int lo   = lane & 15, hi = lane >> 4;
    const int wrp  = wv >> 2, wcp = wv & 3;

    const int srow = lane >> 3;
    const int scol = ((lane & 7) ^ (lane >> 3)) * 8;

    f32x4 acc[4][4];
#pragma unroll
    for (int m = 0; m < 4; ++m)
#pragma unroll
        for (int n = 0; n < 4; ++n)
            acc[m][n] = (f32x4){0.f, 0.f, 0.f, 0.f};

    auto STAGE = [&](int t) {
        const int k0 = t * 64;
        bf16* lb = &lds[(t % 3) * BUF];
#pragma unroll
        for (int j = 0; j < 2; ++j) {
            const int c = wv * 2 + j;
            GLOAD_LDS16(A + (size_t)(brow + c * 8 + srow) * K + k0 + scol, lb + c * 512);
        }
#pragma unroll
        for (int j = 0; j < 4; ++j) {
            const int c = wv * 4 + j;
            GLOAD_LDS16(B + (size_t)(bcol + c * 8 + srow) * K + k0 + scol, lb + ASZ + c * 512);
        }
    };

    const int nt = K / 64;
    STAGE(0); STAGE(1);
    WAITV(6); BAR(); SCHEDB();

    for (int t = 0; t < nt; ++t) {
        const bf16* lb = &lds[(t % 3) * BUF];
        bf16x8 af[4][2], bfr[4][2];
#pragma unroll
        for (int m = 0; m < 4; ++m) {
            const int ru = wrp * 64 + m * 16 + lo;
#pragma unroll
            for (int kk = 0; kk < 2; ++kk)
                af[m][kk] = *(const bf16x8*)&lb[ru * 64 + (((kk * 4 + hi) ^ (lo & 7)) * 8)];
        }
#pragma unroll
        for (int n = 0; n < 4; ++n) {
            const int rb = wcp * 64 + n * 16 + lo;
#pragma unroll
            for (int kk = 0; kk < 2; ++kk)
                bfr[n][kk] = *(const bf16x8*)&lb[ASZ + rb * 64 + (((kk * 4 + hi) ^ (lo & 7)) * 8)];
        }

        if (t + 2 < nt) STAGE(t + 2);

        __builtin_amdgcn_s_setprio(1);
#pragma unroll
        for (int m = 0; m < 4; ++m)
#pragma unroll
            for (int n = 0; n < 4; ++n)
#pragma unroll
                for (int kk = 0; kk < 2; ++kk)
                    acc[m][n] = __builtin_amdgcn_mfma_f32_16x16x32_bf16(af[m][kk], bfr[n][kk], acc[m][n], 0, 0, 0);
        __builtin_amdgcn_s_setprio(0);

        if (t + 2 < nt)      WAITV(6);
        else if (t + 1 < nt) WAITV(0);
        if (t + 1 < nt) { BAR(); SCHEDB(); }
    }

#pragma unroll
    for (int m = 0; m < 4; ++m) {
        const int row = brow + wrp * 64 + m * 16 + hi * 4;
#pragma unroll
        for (int n = 0; n < 4; ++n) {
            const int col = bcol + wcp * 64 + n * 16 + lo;
            const float bv = bias[col];
#pragma unroll
            for (int r = 0; r < 4; ++r) {
                const float v = acc[m][n][r] + bv;
                if (OUT_BF16)
                    ((bf16*)Cout)[(size_t)(row + r) * ldc + col] = (bf16)v;
                else
                    ((float*)Cout)[(size_t)(row + r) * ldc + col] = v;
            }
        }
    }
}

// ---------------- MFMA flash attention: causal + ALiBi, bf16 in/out (r6-verified) ----------------
__global__ __launch_bounds__(512) void attn_mfma(
    const bf16* __restrict__ qkv, bf16* __restrict__ attn_out)
{
    const int S = 2048, QKV = 12288, D = 4096, HD = 128;
    const int bid = blockIdx.x;
    const int h   = bid & 31;
    const int qi  = 15 - (bid >> 5);
    const int q0  = qi * 128;
    const int tid = threadIdx.x;
    const int w    = tid >> 6, lane = tid & 63;
    const int lo   = lane & 15, hi = lane >> 4;
    const int qbase = q0 + w * 16;

    __shared__ bf16 Ks[64 * 128];
    __shared__ bf16 Vs[128 * 72];
    __shared__ bf16 Ps[8 * 16 * 72];

    const float scale = 0.08838834764831845f;
    const float slope = exp2f(-0.25f * (float)(h + 1));

    bf16x8 qfrag[4];
#pragma unroll
    for (int ds = 0; ds < 4; ++ds)
        qfrag[ds] = *(const bf16x8*)(qkv + (size_t)(qbase + lo) * QKV + h * HD + ds * 32 + hi * 8);

    f32x4 o[8];
#pragma unroll
    for (int dt = 0; dt < 8; ++dt) o[dt] = (f32x4){0.f, 0.f, 0.f, 0.f};
    float mrow[4] = {-1e30f, -1e30f, -1e30f, -1e30f};
    float lrow[4] = {0.f, 0.f, 0.f, 0.f};

    const int krow = tid >> 3;
    const int kch  = tid & 7;
    const int vp2  = tid & 63;
    const int voct = tid >> 6;

    const int ntile = (q0 + 128) / 64;
    for (int t = 0; t < ntile; ++t) {
        const int kv0 = t * 64;
        {
            const bf16* kp = qkv + (size_t)(kv0 + krow) * QKV + D + h * HD + kch * 16;
            bf16x8 k0 = *(const bf16x8*)kp;
            bf16x8 k1 = *(const bf16x8*)(kp + 8);
            const int kb  = krow * 128 + kch * 16;
            const int swzk = (krow & 7) << 3;
            *(bf16x8*)&Ks[kb ^ swzk]       = k0;
            *(bf16x8*)&Ks[(kb + 8) ^ swzk] = k1;
        }
        {
            const bf16* vp = qkv + (size_t)(kv0 + voct * 8) * QKV + 2 * D + h * HD + 2 * vp2;
            bf16x8 r0, r1;
#pragma unroll
            for (int j = 0; j < 8; ++j) {
                const unsigned u = *(const unsigned*)(vp + (size_t)j * QKV);
                unsigned short us0 = (unsigned short)(u & 0xffff);
                unsigned short us1 = (unsigned short)(u >> 16);
                r0[j] = *(const bf16*)&us0;
                r1[j] = *(const bf16*)&us1;
            }
            *(bf16x8*)&Vs[(2 * vp2) * 72 + voct * 8]     = r0;
            *(bf16x8*)&Vs[(2 * vp2 + 1) * 72 + voct * 8] = r1;
        }
        __syncthreads();

        if (kv0 <= qbase + 15) {
            f32x4 c[4];
#pragma unroll
            for (int j = 0; j < 4; ++j) c[j] = (f32x4){0.f, 0.f, 0.f, 0.f};
            __builtin_amdgcn_s_setprio(1);
#pragma unroll
            for (int ds = 0; ds < 4; ++ds) {
#pragma unroll
                for (int j = 0; j < 4; ++j) {
                    const int r = j * 16 + lo;
                    bf16x8 b = *(const bf16x8*)&Ks[(r * 128 + ds * 32 + hi * 8) ^ ((r & 7) << 3)];
                    c[j] = __builtin_amdgcn_mfma_f32_16x16x32_bf16(qfrag[ds], b, c[j], 0, 0, 0);
                }
            }
            __builtin_amdgcn_s_setprio(0);
#pragma unroll
            for (int r = 0; r < 4; ++r) {
                const int q = qbase + hi * 4 + r;
                float s[4];
#pragma unroll
                for (int j = 0; j < 4; ++j) {
                    const int ki = kv0 + j * 16 + lo;
                    s[j] = c[j][r] * scale + slope * (float)(ki - (S - 1));
                    if (ki > q) s[j] = -1e30f;
                }
                float tm = fmaxf(fmaxf(s[0], s[1]), fmaxf(s[2], s[3]));
                tm = fmaxf(tm, __shfl_xor(tm, 1));
                tm = fmaxf(tm, __shfl_xor(tm, 2));
                tm = fmaxf(tm, __shfl_xor(tm, 4));
                tm = fmaxf(tm, __shfl_xor(tm, 8));
                const float mnew = fmaxf(mrow[r], tm);
                const float cr = __expf(mrow[r] - mnew);
                float p[4], ps = 0.f;
#pragma unroll
                for (int j = 0; j < 4; ++j) { p[j] = __expf(s[j] - mnew); ps += p[j]; }
                ps += __shfl_xor(ps, 1);
                ps += __shfl_xor(ps, 2);
                ps += __shfl_xor(ps, 4);
                ps += __shfl_xor(ps, 8);
                lrow[r] = lrow[r] * cr + ps;
                mrow[r] = mnew;
#pragma unroll
                for (int dt = 0; dt < 8; ++dt) o[dt][r] *= cr;
#pragma unroll
                for (int j = 0; j < 4; ++j)
                    Ps[w * 1152 + (hi * 4 + r) * 72 + j * 16 + lo] = (bf16)p[j];
            }
            bf16x8 pa0 = *(const bf16x8*)&Ps[w * 1152 + lo * 72 + hi * 8];
            bf16x8 pa1 = *(const bf16x8*)&Ps[w * 1152 + lo * 72 + 32 + hi * 8];
            __builtin_amdgcn_s_setprio(1);
#pragma unroll
            for (int dt = 0; dt < 8; ++dt) {
                bf16x8 bv0 = *(const bf16x8*)&Vs[(dt * 16 + lo) * 72 + hi * 8];
                bf16x8 bv1 = *(const bf16x8*)&Vs[(dt * 16 + lo) * 72 + 32 + hi * 8];
                o[dt] = __builtin_amdgcn_mfma_f32_16x16x32_bf16(pa0, bv0, o[dt], 0, 0, 0);
                o[dt] = __builtin_amdgcn_mfma_f32_16x16x32_bf16(pa1, bv1, o[dt], 0, 0, 0);
            }
            __builtin_amdgcn_s_setprio(0);
        }
        __syncthreads();
    }

#pragma unroll
    for (int r = 0; r < 4; ++r) {
        const float inv = 1.0f / lrow[r];
        const int q = qbase + hi * 4 + r;
        bf16* op = attn_out + (size_t)q * D + h * HD;
#pragma unroll
        for (int dt = 0; dt < 8; ++dt)
            op[dt * 16 + lo] = (bf16)(o[dt][r] * inv);
    }
}

extern "C" void kernel_launch(void* const* d_in, const int* in_sizes, int n_in,
                              void* d_out, int out_size, void* d_ws, size_t ws_size,
                              hipStream_t stream) {
    const int S = 2048, D = 4096, QKV = 12288;
    const int NH = 6144;
    const float* x     = (const float*)d_in[0];
    const float* w_qkv = (const float*)d_in[1];
    const float* b_qkv = (const float*)d_in[2];
    const float* w_out = (const float*)d_in[3];
    const float* b_out = (const float*)d_in[4];
    float* out = (float*)d_out;

    char* ws = (char*)d_ws;
    const size_t need_full = (size_t)S * D * 2 + (size_t)QKV * D * 2 + (size_t)S * QKV * 2;

    if (ws_size >= need_full) {
        bf16* xb    = (bf16*)ws;                                    // [2048][4096]
        bf16* attnb = xb;                                           // reuse after xb dead
        bf16* wqb   = (bf16*)(ws + (size_t)S * D * 2);              // [12288][4096]
        bf16* wob   = wqb;                                          // reuse after wqb dead
        bf16* qkvb  = (bf16*)(ws + (size_t)S * D * 2 + (size_t)QKV * D * 2);  // [2048][12288]

        cvt_f32_bf16<<<2048, 256, 0, stream>>>(x, xb, S * D / 16);
        cvt_f32_bf16<<<4096, 256, 0, stream>>>(w_qkv, wqb, QKV * D / 16);
        // QKV: 48x8 = 384 blocks of 256^2, corrected 8-phase
        gemm_8p<1><<<(QKV / 256) * (S / 256), 512, 0, stream>>>(xb, wqb, b_qkv, qkvb, D, QKV, QKV / 256);
        attn_mfma<<<512, 512, 0, stream>>>(qkvb, attnb);
        cvt_f32_bf16<<<2048, 256, 0, stream>>>(w_out, wob, D * D / 16);
        // out-proj: exact 256-block round, r11-verified structure
        gemm_sp<0><<<(D / 256) * (S / 128), 512, 0, stream>>>(attnb, wob, b_out, out, D, D, D / 256);
    } else {
        bf16* xb    = (bf16*)ws;
        bf16* attnb = xb;
        bf16* wb    = (bf16*)(ws + (size_t)S * D * 2);              // [6144][4096]
        bf16* wob   = wb;
        bf16* qkvb  = (bf16*)(ws + (size_t)S * D * 2 + (size_t)NH * D * 2);

        cvt_f32_bf16<<<2048, 256, 0, stream>>>(x, xb, S * D / 16);
        cvt_f32_bf16<<<2048, 256, 0, stream>>>(w_qkv, wb, NH * D / 16);
        gemm_8p<1><<<(NH / 256) * (S / 256), 512, 0, stream>>>(xb, wb, b_qkv, qkvb, D, QKV, NH / 256);
        cvt_f32_bf16<<<2048, 256, 0, stream>>>(w_qkv + (size_t)NH * D, wb, NH * D / 16);
        gemm_8p<1><<<(NH / 256) * (S / 256), 512, 0, stream>>>(xb, wb, b_qkv + NH, qkvb + NH, D, QKV, NH / 256);
        attn_mfma<<<512, 512, 0, stream>>>(qkvb, attnb);
        cvt_f32_bf16<<<2048, 256, 0, stream>>>(w_out, wob, D * D / 16);
        gemm_sp<0><<<(D / 256) * (S / 128), 512, 0, stream>>>(attnb, wob, b_out, out, D, D, D / 256);
    }
}

// Round 14
// 464.034 us; speedup vs baseline: 1.0033x; 1.0033x over previous
//
#include <hip/hip_runtime.h>
#include <hip/hip_bf16.h>

typedef __bf16 bf16;
typedef __attribute__((ext_vector_type(8))) __bf16 bf16x8;
typedef __attribute__((ext_vector_type(4))) float f32x4;

#define GLOAD_LDS16(g, l)                                                        \
    __builtin_amdgcn_global_load_lds(                                            \
        (const __attribute__((address_space(1))) void*)(g),                      \
        (__attribute__((address_space(3))) void*)(l), 16, 0, 0)

#define WAITV(n) asm volatile("s_waitcnt vmcnt(" #n ")" ::: "memory")
#define BAR()    __builtin_amdgcn_s_barrier()
#define SCHEDB() __builtin_amdgcn_sched_barrier(0)

// ---------------- fp32 -> bf16 conversion (vectorized, grid-stride) ----------------
__global__ __launch_bounds__(256) void cvt_f32_bf16(
    const float* __restrict__ src, bf16* __restrict__ dst, int n16)
{
    int idx = blockIdx.x * 256 + threadIdx.x;
    const int stride = gridDim.x * 256;
    for (int i = idx; i < n16; i += stride) {
        const float* p = src + (size_t)i * 16;
        f32x4 a = *(const f32x4*)p;
        f32x4 b = *(const f32x4*)(p + 4);
        f32x4 c = *(const f32x4*)(p + 8);
        f32x4 d = *(const f32x4*)(p + 12);
        bf16x8 h0, h1;
#pragma unroll
        for (int j = 0; j < 4; ++j) {
            h0[j] = (bf16)a[j]; h0[4 + j] = (bf16)b[j];
            h1[j] = (bf16)c[j]; h1[4 + j] = (bf16)d[j];
        }
        bf16* q = dst + (size_t)i * 16;
        *(bf16x8*)q = h0;
        *(bf16x8*)(q + 8) = h1;
    }
}

// ---- single-phase 3-deep GEMM, BK=32 / 2 blocks-per-CU: C = A[M][K]*B[N][K]^T + bias ----
// BM=128, BN=256, 8 waves (2M x 4N -> per-wave 64x64), r11-verified sync structure.
// Per K-tile (32): {8 ds_read_b128 || stage tile t+2 (3 gloads/wave)} -> 16 MFMA/wave
// -> WAITV(3) -> bar. 3 LDS bufs x 24KB = 72KB -> 2 blocks/CU (16 waves: inter-block
// overlap fills barrier/stage stalls, m114). vmcnt: in-flight t+1(3)+t+2(3)=6, WAITV(3)
// retires t+1; tail WAITV(0); never drains mid-loop.
// Swizzle (r8 HW-verified 0-conflict for 64B rows): phys 16B-slot s of row r holds
// logical slot s ^ ((r>>1)&3); staged via pre-swizzled global col ((l&3)^((l>>3)&3));
// read at slot hi ^ ((lo>>1)&3).
// Block map (nbx%16==0): 256-block window = 16 bx x 16 by; XCD owns 2 bx x 16 by.
template <int OUT_BF16>
__global__ __launch_bounds__(512, 2) void gemm_sp(
    const bf16* __restrict__ A, const bf16* __restrict__ B,
    const float* __restrict__ bias, void* __restrict__ Cout,
    int K, int ldc, int nbx)
{
    constexpr int ASZ = 128 * 32;              // 4096 elems (8KB)
    constexpr int BUF = ASZ + 256 * 32;        // 12288 elems = 24KB
    __shared__ bf16 lds[3 * BUF];              // 72KB -> 2 blocks/CU

    int bx, by;
    if ((nbx & 15) == 0) {
        const int r = (int)blockIdx.x & 255;
        const int slot = r >> 3;                                   // 0..31
        bx = ((int)blockIdx.x >> 8) * 16 + (r & 7) * 2 + (slot >> 4);
        by = slot & 15;
    } else {                                                       // fallback: XCD-chunked
        const int cpx = gridDim.x >> 3;
        const int swz = ((int)blockIdx.x & 7) * cpx + ((int)blockIdx.x >> 3);
        bx = swz % nbx; by = swz / nbx;
    }
    const int brow = by * 128, bcol = bx * 256;

    const int tid  = threadIdx.x;
    const int wv   = tid >> 6, lane = tid & 63;
    const int lo   = lane & 15, hi = lane >> 4;
    const int wrp  = wv >> 2, wcp = wv & 3;           // 2(M) x 4(N); per-wave 64 rows x 64 cols

    const int srow = lane >> 2;                             // row-in-chunk 0..15
    const int scol = ((lane & 3) ^ ((lane >> 3) & 3)) * 8;  // pre-swizzled global col (elems)
    const int rslot = 0;  // placeholder (formula inline below)

    f32x4 acc[4][4];
#pragma unroll
    for (int m = 0; m < 4; ++m)
#pragma unroll
        for (int n = 0; n < 4; ++n)
            acc[m][n] = (f32x4){0.f, 0.f, 0.f, 0.f};

    // stage K-tile t into buf t%3: A 8 chunks (1/wave), B 16 chunks (2/wave); chunk = 16 rows
    auto STAGE = [&](int t) {
        const int k0 = t * 32;
        bf16* lb = &lds[(t % 3) * BUF];
        GLOAD_LDS16(A + (size_t)(brow + wv * 16 + srow) * K + k0 + scol, lb + wv * 512);
#pragma unroll
        for (int j = 0; j < 2; ++j) {
            const int c = wv * 2 + j;
            GLOAD_LDS16(B + (size_t)(bcol + c * 16 + srow) * K + k0 + scol, lb + ASZ + c * 512);
        }
    };

    const int nt = K / 32;   // 128 for K=4096

    STAGE(0); STAGE(1);
    WAITV(3); BAR(); SCHEDB();

    const int rsl = (hi ^ ((lo >> 1) & 3)) * 8;   // read slot offset (elems), r8-verified

    for (int t = 0; t < nt; ++t) {
        const bf16* lb = &lds[(t % 3) * BUF];

        bf16x8 af[4], bfr[4];
#pragma unroll
        for (int m = 0; m < 4; ++m)
            af[m] = *(const bf16x8*)&lb[(wrp * 64 + m * 16 + lo) * 32 + rsl];
#pragma unroll
        for (int n = 0; n < 4; ++n)
            bfr[n] = *(const bf16x8*)&lb[ASZ + (wcp * 64 + n * 16 + lo) * 32 + rsl];

        if (t + 2 < nt) STAGE(t + 2);    // issue early; lands under MFMA of this + next iter

        __builtin_amdgcn_s_setprio(1);
#pragma unroll
        for (int m = 0; m < 4; ++m)
#pragma unroll
            for (int n = 0; n < 4; ++n)
                acc[m][n] = __builtin_amdgcn_mfma_f32_16x16x32_bf16(af[m], bfr[n], acc[m][n], 0, 0, 0);
        __builtin_amdgcn_s_setprio(0);

        if (t + 2 < nt)      WAITV(3);   // retire tile t+1; t+2 stays in flight
        else if (t + 1 < nt) WAITV(0);   // tail
        if (t + 1 < nt) { BAR(); SCHEDB(); }
    }
    (void)rslot;

    // epilogue: C/D layout row=(lane>>4)*4+r, col=lane&15
#pragma unroll
    for (int m = 0; m < 4; ++m) {
        const int row = brow + wrp * 64 + m * 16 + hi * 4;
#pragma unroll
        for (int n = 0; n < 4; ++n) {
            const int col = bcol + wcp * 64 + n * 16 + lo;
            const float bv = bias[col];
#pragma unroll
            for (int r = 0; r < 4; ++r) {
                const float v = acc[m][n][r] + bv;
                if (OUT_BF16)
                    ((bf16*)Cout)[(size_t)(row + r) * ldc + col] = (bf16)v;
                else
                    ((float*)Cout)[(size_t)(row + r) * ldc + col] = v;
            }
        }
    }
}

// ---------------- MFMA flash attention: causal + ALiBi, bf16 in/out (r6-verified) ----------------
__global__ __launch_bounds__(512) void attn_mfma(
    const bf16* __restrict__ qkv, bf16* __restrict__ attn_out)
{
    const int S = 2048, QKV = 12288, D = 4096, HD = 128;
    const int bid = blockIdx.x;
    const int h   = bid & 31;
    const int qi  = 15 - (bid >> 5);
    const int q0  = qi * 128;
    const int tid = threadIdx.x;
    const int w    = tid >> 6, lane = tid & 63;
    const int lo   = lane & 15, hi = lane >> 4;
    const int qbase = q0 + w * 16;

    __shared__ bf16 Ks[64 * 128];
    __shared__ bf16 Vs[128 * 72];
    __shared__ bf16 Ps[8 * 16 * 72];

    const float scale = 0.08838834764831845f;
    const float slope = exp2f(-0.25f * (float)(h + 1));

    bf16x8 qfrag[4];
#pragma unroll
    for (int ds = 0; ds < 4; ++ds)
        qfrag[ds] = *(const bf16x8*)(qkv + (size_t)(qbase + lo) * QKV + h * HD + ds * 32 + hi * 8);

    f32x4 o[8];
#pragma unroll
    for (int dt = 0; dt < 8; ++dt) o[dt] = (f32x4){0.f, 0.f, 0.f, 0.f};
    float mrow[4] = {-1e30f, -1e30f, -1e30f, -1e30f};
    float lrow[4] = {0.f, 0.f, 0.f, 0.f};

    const int krow = tid >> 3;
    const int kch  = tid & 7;
    const int vp2  = tid & 63;
    const int voct = tid >> 6;

    const int ntile = (q0 + 128) / 64;
    for (int t = 0; t < ntile; ++t) {
        const int kv0 = t * 64;
        {
            const bf16* kp = qkv + (size_t)(kv0 + krow) * QKV + D + h * HD + kch * 16;
            bf16x8 k0 = *(const bf16x8*)kp;
            bf16x8 k1 = *(const bf16x8*)(kp + 8);
            const int kb  = krow * 128 + kch * 16;
            const int swzk = (krow & 7) << 3;
            *(bf16x8*)&Ks[kb ^ swzk]       = k0;
            *(bf16x8*)&Ks[(kb + 8) ^ swzk] = k1;
        }
        {
            const bf16* vp = qkv + (size_t)(kv0 + voct * 8) * QKV + 2 * D + h * HD + 2 * vp2;
            bf16x8 r0, r1;
#pragma unroll
            for (int j = 0; j < 8; ++j) {
                const unsigned u = *(const unsigned*)(vp + (size_t)j * QKV);
                unsigned short us0 = (unsigned short)(u & 0xffff);
                unsigned short us1 = (unsigned short)(u >> 16);
                r0[j] = *(const bf16*)&us0;
                r1[j] = *(const bf16*)&us1;
            }
            *(bf16x8*)&Vs[(2 * vp2) * 72 + voct * 8]     = r0;
            *(bf16x8*)&Vs[(2 * vp2 + 1) * 72 + voct * 8] = r1;
        }
        __syncthreads();

        if (kv0 <= qbase + 15) {
            f32x4 c[4];
#pragma unroll
            for (int j = 0; j < 4; ++j) c[j] = (f32x4){0.f, 0.f, 0.f, 0.f};
            __builtin_amdgcn_s_setprio(1);
#pragma unroll
            for (int ds = 0; ds < 4; ++ds) {
#pragma unroll
                for (int j = 0; j < 4; ++j) {
                    const int r = j * 16 + lo;
                    bf16x8 b = *(const bf16x8*)&Ks[(r * 128 + ds * 32 + hi * 8) ^ ((r & 7) << 3)];
                    c[j] = __builtin_amdgcn_mfma_f32_16x16x32_bf16(qfrag[ds], b, c[j], 0, 0, 0);
                }
            }
            __builtin_amdgcn_s_setprio(0);
#pragma unroll
            for (int r = 0; r < 4; ++r) {
                const int q = qbase + hi * 4 + r;
                float s[4];
#pragma unroll
                for (int j = 0; j < 4; ++j) {
                    const int ki = kv0 + j * 16 + lo;
                    s[j] = c[j][r] * scale + slope * (float)(ki - (S - 1));
                    if (ki > q) s[j] = -1e30f;
                }
                float tm = fmaxf(fmaxf(s[0], s[1]), fmaxf(s[2], s[3]));
                tm = fmaxf(tm, __shfl_xor(tm, 1));
                tm = fmaxf(tm, __shfl_xor(tm, 2));
                tm = fmaxf(tm, __shfl_xor(tm, 4));
                tm = fmaxf(tm, __shfl_xor(tm, 8));
                const float mnew = fmaxf(mrow[r], tm);
                const float cr = __expf(mrow[r] - mnew);
                float p[4], ps = 0.f;
#pragma unroll
                for (int j = 0; j < 4; ++j) { p[j] = __expf(s[j] - mnew); ps += p[j]; }
                ps += __shfl_xor(ps, 1);
                ps += __shfl_xor(ps, 2);
                ps += __shfl_xor(ps, 4);
                ps += __shfl_xor(ps, 8);
                lrow[r] = lrow[r] * cr + ps;
                mrow[r] = mnew;
#pragma unroll
                for (int dt = 0; dt < 8; ++dt) o[dt][r] *= cr;
#pragma unroll
                for (int j = 0; j < 4; ++j)
                    Ps[w * 1152 + (hi * 4 + r) * 72 + j * 16 + lo] = (bf16)p[j];
            }
            bf16x8 pa0 = *(const bf16x8*)&Ps[w * 1152 + lo * 72 + hi * 8];
            bf16x8 pa1 = *(const bf16x8*)&Ps[w * 1152 + lo * 72 + 32 + hi * 8];
            __builtin_amdgcn_s_setprio(1);
#pragma unroll
            for (int dt = 0; dt < 8; ++dt) {
                bf16x8 bv0 = *(const bf16x8*)&Vs[(dt * 16 + lo) * 72 + hi * 8];
                bf16x8 bv1 = *(const bf16x8*)&Vs[(dt * 16 + lo) * 72 + 32 + hi * 8];
                o[dt] = __builtin_amdgcn_mfma_f32_16x16x32_bf16(pa0, bv0, o[dt], 0, 0, 0);
                o[dt] = __builtin_amdgcn_mfma_f32_16x16x32_bf16(pa1, bv1, o[dt], 0, 0, 0);
            }
            __builtin_amdgcn_s_setprio(0);
        }
        __syncthreads();
    }

#pragma unroll
    for (int r = 0; r < 4; ++r) {
        const float inv = 1.0f / lrow[r];
        const int q = qbase + hi * 4 + r;
        bf16* op = attn_out + (size_t)q * D + h * HD;
#pragma unroll
        for (int dt = 0; dt < 8; ++dt)
            op[dt * 16 + lo] = (bf16)(o[dt][r] * inv);
    }
}

extern "C" void kernel_launch(void* const* d_in, const int* in_sizes, int n_in,
                              void* d_out, int out_size, void* d_ws, size_t ws_size,
                              hipStream_t stream) {
    const int S = 2048, D = 4096, QKV = 12288;
    const int NH = 6144;
    const float* x     = (const float*)d_in[0];
    const float* w_qkv = (const float*)d_in[1];
    const float* b_qkv = (const float*)d_in[2];
    const float* w_out = (const float*)d_in[3];
    const float* b_out = (const float*)d_in[4];
    float* out = (float*)d_out;

    char* ws = (char*)d_ws;
    const size_t need_full = (size_t)S * D * 2 + (size_t)QKV * D * 2 + (size_t)S * QKV * 2;

    if (ws_size >= need_full) {
        bf16* xb    = (bf16*)ws;                                    // [2048][4096]
        bf16* attnb = xb;                                           // reuse after xb dead
        bf16* wqb   = (bf16*)(ws + (size_t)S * D * 2);              // [12288][4096]
        bf16* wob   = wqb;                                          // reuse after wqb dead
        bf16* qkvb  = (bf16*)(ws + (size_t)S * D * 2 + (size_t)QKV * D * 2);  // [2048][12288]

        cvt_f32_bf16<<<2048, 256, 0, stream>>>(x, xb, S * D / 16);
        cvt_f32_bf16<<<4096, 256, 0, stream>>>(w_qkv, wqb, QKV * D / 16);
        gemm_sp<1><<<(QKV / 256) * (S / 128), 512, 0, stream>>>(xb, wqb, b_qkv, qkvb, D, QKV, QKV / 256);
        attn_mfma<<<512, 512, 0, stream>>>(qkvb, attnb);
        cvt_f32_bf16<<<2048, 256, 0, stream>>>(w_out, wob, D * D / 16);
        gemm_sp<0><<<(D / 256) * (S / 128), 512, 0, stream>>>(attnb, wob, b_out, out, D, D, D / 256);
    } else {
        bf16* xb    = (bf16*)ws;
        bf16* attnb = xb;
        bf16* wb    = (bf16*)(ws + (size_t)S * D * 2);              // [6144][4096]
        bf16* wob   = wb;
        bf16* qkvb  = (bf16*)(ws + (size_t)S * D * 2 + (size_t)NH * D * 2);

        cvt_f32_bf16<<<2048, 256, 0, stream>>>(x, xb, S * D / 16);
        cvt_f32_bf16<<<2048, 256, 0, stream>>>(w_qkv, wb, NH * D / 16);
        gemm_sp<1><<<(NH / 256) * (S / 128), 512, 0, stream>>>(xb, wb, b_qkv, qkvb, D, QKV, NH / 256);
        cvt_f32_bf16<<<2048, 256, 0, stream>>>(w_qkv + (size_t)NH * D, wb, NH * D / 16);
        gemm_sp<1><<<(NH / 256) * (S / 128), 512, 0, stream>>>(xb, wb, b_qkv + NH, qkvb + NH, D, QKV, NH / 256);
        attn_mfma<<<512, 512, 0, stream>>>(qkvb, attnb);
        cvt_f32_bf16<<<2048, 256, 0, stream>>>(w_out, wob, D * D / 16);
        gemm_sp<0><<<(D / 256) * (S / 128), 512, 0, stream>>>(attnb, wob, b_out, out, D, D, D / 256);
    }
}